// Round 8
// baseline (75.423 us; speedup 1.0000x reference)
//
#include <hip/hip_runtime.h>
#include <math.h>

#define BSZ 512
#define DSZ 512
#define MARGIN 0.4f
#define ALPHA 1.0f
#define MB 16            // anchor rows per strip block
#define NSTRIP (BSZ/MB)  // 32 strip blocks

typedef __attribute__((ext_vector_type(8))) short bf16x8;
typedef __attribute__((ext_vector_type(4))) float f32x4;

static __device__ __forceinline__ unsigned short f2bf(float f) {
    // round-to-nearest-even bf16
    unsigned int u = __float_as_uint(f);
    unsigned int r = (u + 0x7fff + ((u >> 16) & 1)) >> 16;
    return (unsigned short)r;
}

// ---------- K1: f32 -> bf16 convert + exact f32 row inv-norms ----------
// 128 blocks x 256 threads; one wave per row.
__global__ __launch_bounds__(256) void rll_prep(const float* __restrict__ emb,
                                                unsigned short* __restrict__ ebf,
                                                float* __restrict__ inv_norm,
                                                int* __restrict__ counter) {
    const int w = threadIdx.x >> 6, l = threadIdx.x & 63;
    const int row = blockIdx.x * 4 + w;
    if (blockIdx.x == 0 && threadIdx.x == 0) counter[0] = 0;   // re-arm per replay
    const float4* src = (const float4*)(emb + (size_t)row * DSZ);
    const float4 v0 = src[l * 2];
    const float4 v1 = src[l * 2 + 1];
    float ss = v0.x * v0.x + v0.y * v0.y + v0.z * v0.z + v0.w * v0.w
             + v1.x * v1.x + v1.y * v1.y + v1.z * v1.z + v1.w * v1.w;
    union { unsigned short u[8]; uint4 q; } pk;
    pk.u[0] = f2bf(v0.x); pk.u[1] = f2bf(v0.y);
    pk.u[2] = f2bf(v0.z); pk.u[3] = f2bf(v0.w);
    pk.u[4] = f2bf(v1.x); pk.u[5] = f2bf(v1.y);
    pk.u[6] = f2bf(v1.z); pk.u[7] = f2bf(v1.w);
    *(uint4*)(ebf + (size_t)row * DSZ + l * 8) = pk.q;
    #pragma unroll
    for (int off = 32; off > 0; off >>= 1) ss += __shfl_down(ss, off);
    if (l == 0) inv_norm[row] = 1.0f / fmaxf(sqrtf(ss), 1e-12f);
}

// ---------- K2: strip Gram (MFMA, B-frags straight from L2) + count ----
// 32 blocks x 512 threads (8 waves). Block b owns anchor rows
// [16b, 16b+16); wave w owns cols [64w, 64w+64). dist row stays in LDS.
__global__ __launch_bounds__(512) void rll_strip(const unsigned short* __restrict__ ebf,
                                                 const float* __restrict__ inv_norm,
                                                 const int* __restrict__ labels,
                                                 float* __restrict__ partial,
                                                 int* __restrict__ counter,
                                                 float* __restrict__ out) {
    __shared__ float dsh[MB][514];   // pad 2: conflict-free epilogue + count
    __shared__ int   lsh[BSZ];
    __shared__ float invs[BSZ];
    __shared__ int   pos[MB][128];
    __shared__ int   np[MB];
    __shared__ float wacc[8];
    __shared__ bool  last;

    const int tid = threadIdx.x;
    const int w = tid >> 6, l = tid & 63;
    const int I0 = blockIdx.x * MB;

    lsh[tid]  = labels[tid];
    invs[tid] = inv_norm[tid];
    if (tid < MB) np[tid] = 0;
    __syncthreads();

    // positive lists: thread t scans candidate column t for all 16 anchors
    #pragma unroll
    for (int m = 0; m < MB; ++m) {
        if (lsh[tid] == lsh[I0 + m] && tid != I0 + m) {
            const int idx = atomicAdd(&np[m], 1);
            if (idx < 128) pos[m][idx] = tid;
        }
    }

    // ---- MFMA strip: D[m][j], m=(l>>4)*4+reg, j=l&15 (R7-verified map) ----
    const int fr  = l & 15;
    const int fkb = (l >> 4) * 8;     // k-offset within 32-chunk
    bf16x8 afrag[16];
    #pragma unroll
    for (int kc = 0; kc < 16; ++kc)
        afrag[kc] = *(const bf16x8*)(ebf + (size_t)(I0 + fr) * DSZ + kc * 32 + fkb);

    f32x4 acc[4];
    #pragma unroll
    for (int ct = 0; ct < 4; ++ct) acc[ct] = (f32x4){0.f, 0.f, 0.f, 0.f};
    #pragma unroll
    for (int kc = 0; kc < 16; ++kc) {
        #pragma unroll
        for (int ct = 0; ct < 4; ++ct) {
            const int j = w * 64 + ct * 16 + fr;
            const bf16x8 b = *(const bf16x8*)(ebf + (size_t)j * DSZ + kc * 32 + fkb);
            acc[ct] = __builtin_amdgcn_mfma_f32_16x16x32_bf16(afrag[kc], b, acc[ct], 0, 0, 0);
        }
    }

    // epilogue: dist into LDS
    #pragma unroll
    for (int ct = 0; ct < 4; ++ct) {
        const int j = w * 64 + ct * 16 + fr;
        const float ij = invs[j];
        #pragma unroll
        for (int r = 0; r < 4; ++r) {
            const int m = ((l >> 4) << 2) + r;
            dsh[m][j] = sqrtf(fmaxf(2.0f - 2.0f * acc[ct][r] * invs[I0 + m] * ij, 0.0f));
        }
    }
    __syncthreads();   // dsh + pos complete

    // ---- counting: wave w handles anchors 2w, 2w+1 ----
    float accl = 0.f;
    #pragma unroll
    for (int s = 0; s < 2; ++s) {
        const int a = w * 2 + s;
        const int li = lsh[I0 + a];
        const int n = min(np[a], 128);
        for (int p = 0; p < n; ++p) {
            const int j = pos[a][p];
            const float thr = dsh[a][j] + MARGIN;
            int cnt = 0;
            #pragma unroll
            for (int q = 0; q < 8; ++q) {
                const int k = l + q * 64;
                cnt += (lsh[k] != li && dsh[a][k] < thr) ? 1 : 0;
            }
            #pragma unroll
            for (int off = 32; off > 0; off >>= 1) cnt += __shfl_down(cnt, off);
            if (l == 0 && cnt > 0) accl += log1pf((float)cnt);
        }
    }
    if (l == 0) wacc[w] = accl;
    __syncthreads();

    if (tid == 0) {
        float t = 0.f;
        #pragma unroll
        for (int q = 0; q < 8; ++q) t += wacc[q];
        partial[blockIdx.x] = t;
        __threadfence();
        const int old = atomicAdd(counter, 1);
        last = (old == NSTRIP - 1);
    }
    __syncthreads();

    if (last) {
        __threadfence();
        if (tid < 64) {
            volatile const float* vp = (volatile const float*)partial;
            float s = (tid < NSTRIP) ? vp[tid] : 0.f;
            #pragma unroll
            for (int off = 32; off > 0; off >>= 1) s += __shfl_down(s, off);
            if (tid == 0) out[0] = s * (ALPHA / (512.0f + 1e-8f));
        }
    }
}

extern "C" void kernel_launch(void* const* d_in, const int* in_sizes, int n_in,
                              void* d_out, int out_size, void* d_ws, size_t ws_size,
                              hipStream_t stream) {
    const float* emb    = (const float*)d_in[0];
    const int*   labels = (const int*)d_in[1];
    float* out = (float*)d_out;

    // ws: ebf (512*512 bf16) | inv_norm (512 f32) | partial (32 f32) | counter
    unsigned short* ebf = (unsigned short*)d_ws;
    float* inv_norm = (float*)(ebf + (size_t)BSZ * DSZ);
    float* partial  = inv_norm + BSZ;
    int*   counter  = (int*)(partial + NSTRIP);

    rll_prep<<<128, 256, 0, stream>>>(emb, ebf, inv_norm, counter);
    rll_strip<<<NSTRIP, 512, 0, stream>>>(ebf, inv_norm, labels, partial, counter, out);
}

// Round 9
// 42.822 us; speedup vs baseline: 1.7613x; 1.7613x over previous
//
#include <hip/hip_runtime.h>
#include <math.h>

#define BSZ 512
#define DSZ 512
#define MARGIN 0.4f
#define ALPHA 1.0f
#define NBLK 256   // 2 anchors per block

// ---- K1: fused dot-products + norms + dist (LDS-only) + counting ----
// 256 blocks x 512 threads (8 waves). Block b owns anchors {2b, 2b+1}.
// Thread tid owns column j = tid: accumulates dot(i0,j), dot(i1,j), ssq_j.
// Anchor-row operands are wave-uniform (scalar loads). dist rows live in
// LDS only; counting happens in-block; one partial per block.
__global__ __launch_bounds__(512) void rll_fused(const float* __restrict__ emb,
                                                 const int* __restrict__ labels,
                                                 float* __restrict__ partial) {
    __shared__ float dsh[2][BSZ];
    __shared__ float ssqs[BSZ];
    __shared__ int   lsh[BSZ];
    __shared__ int   pos[2][128];
    __shared__ int   np[2];
    __shared__ float wacc[8];

    const int tid = threadIdx.x;          // 0..511 == column j
    const int w = tid >> 6, l = tid & 63;
    const int i0 = blockIdx.x * 2, i1 = i0 + 1;

    lsh[tid] = labels[tid];
    if (tid < 2) np[tid] = 0;
    __syncthreads();

    const int l0 = lsh[i0], l1 = lsh[i1];
    // positive lists (order nondeterministic; set is deterministic)
    if (lsh[tid] == l0 && tid != i0) pos[0][atomicAdd(&np[0], 1) & 127] = tid;
    if (lsh[tid] == l1 && tid != i1) pos[1][atomicAdd(&np[1], 1) & 127] = tid;

    // ---- dot products: col j streamed as float2, anchors wave-uniform ----
    const float* __restrict__ row0 = emb + (size_t)i0 * DSZ;
    const float* __restrict__ row1 = emb + (size_t)i1 * DSZ;
    const float2* __restrict__ colp = (const float2*)(emb + (size_t)tid * DSZ);
    float acc0 = 0.f, acc1 = 0.f, ssq = 0.f;
    #pragma unroll 8
    for (int kh = 0; kh < DSZ / 2; ++kh) {
        const float2 c = colp[kh];
        const float a0x = row0[2 * kh], a0y = row0[2 * kh + 1];
        const float a1x = row1[2 * kh], a1y = row1[2 * kh + 1];
        acc0 = fmaf(c.y, a0y, fmaf(c.x, a0x, acc0));
        acc1 = fmaf(c.y, a1y, fmaf(c.x, a1x, acc1));
        ssq  = fmaf(c.y, c.y, fmaf(c.x, c.x, ssq));
    }
    ssqs[tid] = ssq;
    __syncthreads();

    const float inv_c = 1.0f / fmaxf(sqrtf(ssq), 1e-12f);
    const float inv0  = 1.0f / fmaxf(sqrtf(ssqs[i0]), 1e-12f);
    const float inv1  = 1.0f / fmaxf(sqrtf(ssqs[i1]), 1e-12f);
    dsh[0][tid] = sqrtf(fmaxf(2.0f - 2.0f * acc0 * inv0 * inv_c, 0.0f));
    dsh[1][tid] = sqrtf(fmaxf(2.0f - 2.0f * acc1 * inv1 * inv_c, 0.0f));
    __syncthreads();

    // ---- counting: anchor s = w&1; waves stride the positive list ----
    const int s = w & 1;
    const int li = s ? l1 : l0;
    const int n = min(np[s], 128);
    float accl = 0.f;
    for (int p = (w >> 1); p < n; p += 4) {
        const int jj = pos[s][p];
        const float thr = dsh[s][jj] + MARGIN;
        int cnt = 0;
        #pragma unroll
        for (int q = 0; q < 8; ++q) {
            const int k = l + q * 64;
            cnt += (lsh[k] != li && dsh[s][k] < thr) ? 1 : 0;
        }
        #pragma unroll
        for (int off = 32; off > 0; off >>= 1) cnt += __shfl_down(cnt, off);
        if (l == 0 && cnt > 0) accl += log1pf((float)cnt);
    }
    if (l == 0) wacc[w] = accl;
    __syncthreads();

    if (tid == 0) {
        float t = 0.f;
        #pragma unroll
        for (int q = 0; q < 8; ++q) t += wacc[q];
        partial[blockIdx.x] = t;   // unconditional: every slot written each call
    }
}

// ---- K2: 256-partial reduce -> out[0] ----
__global__ __launch_bounds__(256) void rll_reduce(const float* __restrict__ partial,
                                                  float* __restrict__ out) {
    __shared__ float wsum[4];
    const int tid = threadIdx.x;
    float s = partial[tid];
    #pragma unroll
    for (int off = 32; off > 0; off >>= 1) s += __shfl_down(s, off);
    if ((tid & 63) == 0) wsum[tid >> 6] = s;
    __syncthreads();
    if (tid == 0)
        out[0] = (wsum[0] + wsum[1] + wsum[2] + wsum[3]) *
                 (ALPHA / (512.0f + 1e-8f));
}

extern "C" void kernel_launch(void* const* d_in, const int* in_sizes, int n_in,
                              void* d_out, int out_size, void* d_ws, size_t ws_size,
                              hipStream_t stream) {
    const float* emb    = (const float*)d_in[0];
    const int*   labels = (const int*)d_in[1];
    float* out = (float*)d_out;

    // ws: partial (256 f32)
    float* partial = (float*)d_ws;

    rll_fused<<<NBLK, 512, 0, stream>>>(emb, labels, partial);
    rll_reduce<<<1, 256, 0, stream>>>(partial, out);
}

// Round 10
// 30.092 us; speedup vs baseline: 2.5064x; 1.4230x over previous
//
#include <hip/hip_runtime.h>
#include <math.h>

#define BSZ 512
#define DSZ 512
#define MARGIN 0.4f
#define ALPHA 1.0f
#define NBLK 256   // 2 anchors per block

// ---- K0: packed transpose  PT[k4][j] = float4(emb[j][4k4..4k4+3]) ----
// 8x8 grid of 64x64 tiles, 256 threads each.
__global__ __launch_bounds__(256) void rll_transpose(const float* __restrict__ emb,
                                                     float* __restrict__ pt) {
    __shared__ float tile[64][65];
    const int tx = threadIdx.x & 15;          // col-quad within tile
    const int ty = threadIdx.x >> 4;          // 0..15
    const int r0 = blockIdx.y * 64, c0 = blockIdx.x * 64;
    #pragma unroll
    for (int rr = 0; rr < 64; rr += 16) {
        const float4 v = *(const float4*)(emb + (size_t)(r0 + ty + rr) * DSZ + c0 + tx * 4);
        tile[ty + rr][tx * 4 + 0] = v.x;
        tile[ty + rr][tx * 4 + 1] = v.y;
        tile[ty + rr][tx * 4 + 2] = v.z;
        tile[ty + rr][tx * 4 + 3] = v.w;
    }
    __syncthreads();
    // write: thread (jj, kq) emits 4 float4s at consecutive j -> coalesced
    const int jj = threadIdx.x & 63;          // j within tile
    const int kq = threadIdx.x >> 6;          // 0..3
    #pragma unroll
    for (int kq2 = 0; kq2 < 4; ++kq2) {
        const int kc = (kq * 4 + kq2) * 4;    // k within tile (x4)
        const float4 v = make_float4(tile[jj][kc + 0], tile[jj][kc + 1],
                                     tile[jj][kc + 2], tile[jj][kc + 3]);
        const int k4 = (c0 >> 2) + kq * 4 + kq2;
        *(float4*)(pt + ((size_t)k4 * BSZ + r0 + jj) * 4) = v;
    }
}

// ---- K1: fused dots (coalesced) + norms + dist-in-LDS + counting ----
// 256 blocks x 512 threads (8 waves). Block b owns anchors {2b, 2b+1}.
// Thread tid owns column j = tid; streams PT coalesced; anchors are
// wave-uniform scalar loads from row-major emb.
__global__ __launch_bounds__(512) void rll_fused(const float* __restrict__ emb,
                                                 const float* __restrict__ pt,
                                                 const int* __restrict__ labels,
                                                 float* __restrict__ partial) {
    __shared__ float dsh[2][BSZ];
    __shared__ float ssqs[BSZ];
    __shared__ int   lsh[BSZ];
    __shared__ int   pos[2][128];
    __shared__ int   np[2];
    __shared__ float wacc[8];

    const int tid = threadIdx.x;          // 0..511 == column j
    const int w = tid >> 6, l = tid & 63;
    const int i0 = blockIdx.x * 2, i1 = i0 + 1;

    lsh[tid] = labels[tid];
    if (tid < 2) np[tid] = 0;
    __syncthreads();

    const int l0 = lsh[i0], l1 = lsh[i1];
    if (lsh[tid] == l0 && tid != i0) pos[0][atomicAdd(&np[0], 1) & 127] = tid;
    if (lsh[tid] == l1 && tid != i1) pos[1][atomicAdd(&np[1], 1) & 127] = tid;

    // ---- dot products: PT rows coalesced, anchor quads uniform ----
    const float4* __restrict__ ptp = (const float4*)pt;          // [k4*512 + j]
    const float4* __restrict__ a0p = (const float4*)(emb + (size_t)i0 * DSZ);
    const float4* __restrict__ a1p = (const float4*)(emb + (size_t)i1 * DSZ);
    float acc0 = 0.f, acc1 = 0.f, ssq = 0.f;
    #pragma unroll 8
    for (int k4 = 0; k4 < DSZ / 4; ++k4) {
        const float4 c  = ptp[(size_t)k4 * BSZ + tid];
        const float4 a0 = a0p[k4];
        const float4 a1 = a1p[k4];
        acc0 = fmaf(c.w, a0.w, fmaf(c.z, a0.z, fmaf(c.y, a0.y, fmaf(c.x, a0.x, acc0))));
        acc1 = fmaf(c.w, a1.w, fmaf(c.z, a1.z, fmaf(c.y, a1.y, fmaf(c.x, a1.x, acc1))));
        ssq  = fmaf(c.w, c.w,  fmaf(c.z, c.z,  fmaf(c.y, c.y,  fmaf(c.x, c.x,  ssq))));
    }
    ssqs[tid] = ssq;
    __syncthreads();

    const float inv_c = 1.0f / fmaxf(sqrtf(ssq), 1e-12f);
    const float inv0  = 1.0f / fmaxf(sqrtf(ssqs[i0]), 1e-12f);
    const float inv1  = 1.0f / fmaxf(sqrtf(ssqs[i1]), 1e-12f);
    dsh[0][tid] = sqrtf(fmaxf(2.0f - 2.0f * acc0 * inv0 * inv_c, 0.0f));
    dsh[1][tid] = sqrtf(fmaxf(2.0f - 2.0f * acc1 * inv1 * inv_c, 0.0f));
    __syncthreads();

    // ---- counting: anchor s = w&1; waves stride the positive list ----
    const int s = w & 1;
    const int li = s ? l1 : l0;
    const int n = min(np[s], 128);
    float accl = 0.f;
    for (int p = (w >> 1); p < n; p += 4) {
        const int jj = pos[s][p];
        const float thr = dsh[s][jj] + MARGIN;
        int cnt = 0;
        #pragma unroll
        for (int q = 0; q < 8; ++q) {
            const int k = l + q * 64;
            cnt += (lsh[k] != li && dsh[s][k] < thr) ? 1 : 0;
        }
        #pragma unroll
        for (int off = 32; off > 0; off >>= 1) cnt += __shfl_down(cnt, off);
        if (l == 0 && cnt > 0) accl += log1pf((float)cnt);
    }
    if (l == 0) wacc[w] = accl;
    __syncthreads();

    if (tid == 0) {
        float t = 0.f;
        #pragma unroll
        for (int q = 0; q < 8; ++q) t += wacc[q];
        partial[blockIdx.x] = t;   // unconditional: every slot written each call
    }
}

// ---- K2: 256-partial reduce -> out[0] ----
__global__ __launch_bounds__(256) void rll_reduce(const float* __restrict__ partial,
                                                  float* __restrict__ out) {
    __shared__ float wsum[4];
    const int tid = threadIdx.x;
    float s = partial[tid];
    #pragma unroll
    for (int off = 32; off > 0; off >>= 1) s += __shfl_down(s, off);
    if ((tid & 63) == 0) wsum[tid >> 6] = s;
    __syncthreads();
    if (tid == 0)
        out[0] = (wsum[0] + wsum[1] + wsum[2] + wsum[3]) *
                 (ALPHA / (512.0f + 1e-8f));
}

extern "C" void kernel_launch(void* const* d_in, const int* in_sizes, int n_in,
                              void* d_out, int out_size, void* d_ws, size_t ws_size,
                              hipStream_t stream) {
    const float* emb    = (const float*)d_in[0];
    const int*   labels = (const int*)d_in[1];
    float* out = (float*)d_out;

    // ws: pt (512*512 f32, packed transpose) | partial (256 f32)
    float* pt      = (float*)d_ws;
    float* partial = pt + (size_t)BSZ * DSZ;

    rll_transpose<<<dim3(8, 8), 256, 0, stream>>>(emb, pt);
    rll_fused<<<NBLK, 512, 0, stream>>>(emb, pt, labels, partial);
    rll_reduce<<<1, 256, 0, stream>>>(partial, out);
}